// Round 8
// baseline (85.007 us; speedup 1.0000x reference)
//
#include <hip/hip_runtime.h>
#include <math.h>

#define EPS 1e-9f

// P[i]: circle i<Nc -> (x, y, radius, 0); box -> (x, y, half.x, half.y).
// Also seeds out with base positions (collide atomically adds corrections).
__global__ void prep(const float2* __restrict__ cpos,
                     const float*  __restrict__ crad,
                     const float2* __restrict__ apos,
                     const float2* __restrict__ ahalf,
                     float4* __restrict__ P,
                     float2* __restrict__ out,
                     int Nc, int Ntot) {
    int i = blockIdx.x * blockDim.x + threadIdx.x;
    if (i >= Ntot) return;
    if (i < Nc) {
        const float2 p = cpos[i];
        P[i]   = make_float4(p.x, p.y, crad[i], 0.0f);
        out[i] = p;
    } else {
        const float2 a = apos[i - Nc];
        const float2 h = ahalf[i - Nc];
        P[i]   = make_float4(a.x, a.y, h.x, h.y);
        out[i] = a;
    }
}

// ---- pair kernels (branchless; EPS guard where self/degenerate possible) ----
__device__ __forceinline__ void cc_pair(float px, float py, float ri,
                                        const float4& q, float& ax, float& ay) {
    const float dx = px - q.x, dy = py - q.y;
    const float d2 = fmaf(dx, dx, dy * dy);
    const float r  = __builtin_amdgcn_rsqf(d2);
    const float t  = fmaf(-d2, r, ri + q.z);
    float s = fmaxf(0.5f * t * r, 0.0f);
    s = (d2 > EPS) ? s : 0.0f;                 // self-pair / coincident guard
    ax = fmaf(s, dx, ax); ay = fmaf(s, dy, ay);
}
__device__ __forceinline__ void cb_pair(float px, float py, float ri,
                                        const float4& q, float& ax, float& ay) {
    const float rx = px - q.x, ry = py - q.y;
    const float cx = fminf(fmaxf(rx, -q.z), q.z);
    const float cy = fminf(fmaxf(ry, -q.w), q.w);
    const float dx = rx - cx, dy = ry - cy;
    const float d2 = fmaf(dx, dx, dy * dy);
    const float r  = __builtin_amdgcn_rsqf(d2);
    const float t  = fmaf(-d2, r, ri);
    float s = fmaxf(0.5f * t * r, 0.0f);
    s = (d2 > EPS) ? s : 0.0f;                 // center-inside-box guard
    ax = fmaf(s, dx, ax); ay = fmaf(s, dy, ay);
}
__device__ __forceinline__ void bc_pair(float bx, float by, float hx, float hy,
                                        const float4& q, float& ax, float& ay) {
    const float rx = q.x - bx, ry = q.y - by;
    const float cx = fminf(fmaxf(rx, -hx), hx);
    const float cy = fminf(fmaxf(ry, -hy), hy);
    const float dx = rx - cx, dy = ry - cy;
    const float d2 = fmaf(dx, dx, dy * dy);
    const float r  = __builtin_amdgcn_rsqf(d2);
    const float t  = fmaf(-d2, r, q.z);
    float s = fmaxf(0.5f * t * r, 0.0f);
    s = (d2 > EPS) ? s : 0.0f;
    ax = fmaf(-s, dx, ax); ay = fmaf(-s, dy, ay);   // opposite on box
}
__device__ __forceinline__ void bb_pair(int j, int i, float bx, float by,
                                        float hx, float hy,
                                        const float4& q, float& ax, float& ay) {
    const float dax = bx - q.x, day = by - q.y;
    const float ovx = (hx + q.z) - fabsf(dax);
    const float ovy = (hy + q.w) - fabsf(day);
    const bool hit = (j != i) && (fminf(ovx, ovy) > 0.0f);
    const bool ux  = ovx <= ovy;
    ax += (hit && ux)  ? copysignf(0.5f * ovx, dax) : 0.0f;
    ay += (hit && !ux) ? copysignf(0.5f * ovy, day) : 0.0f;
}

// Lane-per-body; each wave owns one 128-partner window (chunk-pair m), fused as
// two independent 64-partner scalar-load streams (j1=128m+k, j2=128m+64+k) for
// 2x ILP between dependent chains. Both halves of a 128-aligned window are the
// same type (Nc=4096 is 128-aligned) -> uniform branches only. No LDS, no
// __syncthreads; each wave atomics its partial directly.
__global__ __launch_bounds__(256)
void collide(const float4* __restrict__ P,
             float* __restrict__ out,
             int Nc) {
    const int lane  = threadIdx.x & 63;
    const int w     = threadIdx.x >> 6;
    const int ibase = (int)(blockIdx.x << 6);
    const int i     = ibase + lane;

    const int m  = blockIdx.y * 4 + w;     // chunk-pair id, 0..47 (uniform)
    const int jb = m << 7;                 // 128-aligned partner window

    const float4 me = P[i];
    float ax = 0.0f, ay = 0.0f;

    const bool bodyC = ibase < Nc;         // uniform
    const bool partC = jb < Nc;            // uniform (whole window same type)

    if (bodyC) {
        const float px = me.x, py = me.y, ri = me.z;
        if (partC) {
            #pragma unroll 4
            for (int k = 0; k < 64; ++k) {
                const float4 q1 = P[jb + k];        // uniform -> s_load
                const float4 q2 = P[jb + 64 + k];   // independent stream
                cc_pair(px, py, ri, q1, ax, ay);
                cc_pair(px, py, ri, q2, ax, ay);
            }
        } else {
            #pragma unroll 4
            for (int k = 0; k < 64; ++k) {
                const float4 q1 = P[jb + k];
                const float4 q2 = P[jb + 64 + k];
                cb_pair(px, py, ri, q1, ax, ay);
                cb_pair(px, py, ri, q2, ax, ay);
            }
        }
    } else {
        const float bx = me.x, by = me.y, hx = me.z, hy = me.w;
        if (partC) {
            #pragma unroll 4
            for (int k = 0; k < 64; ++k) {
                const float4 q1 = P[jb + k];
                const float4 q2 = P[jb + 64 + k];
                bc_pair(bx, by, hx, hy, q1, ax, ay);
                bc_pair(bx, by, hx, hy, q2, ax, ay);
            }
        } else {
            #pragma unroll 4
            for (int k = 0; k < 64; ++k) {
                const float4 q1 = P[jb + k];
                const float4 q2 = P[jb + 64 + k];
                bb_pair(jb + k,      i, bx, by, hx, hy, q1, ax, ay);
                bb_pair(jb + 64 + k, i, bx, by, hx, hy, q2, ax, ay);
            }
        }
    }

    atomicAdd(&out[2 * i],     ax);
    atomicAdd(&out[2 * i + 1], ay);
}

extern "C" void kernel_launch(void* const* d_in, const int* in_sizes, int n_in,
                              void* d_out, int out_size, void* d_ws, size_t ws_size,
                              hipStream_t stream) {
    (void)n_in; (void)out_size; (void)ws_size;

    const float2* cpos  = (const float2*)d_in[0];
    const float*  crad  = (const float*) d_in[1];
    const float2* apos  = (const float2*)d_in[2];
    const float2* ahalf = (const float2*)d_in[3];

    const int Nc   = in_sizes[1];       // 4096
    const int Na   = in_sizes[2] / 2;   // 2048
    const int Ntot = Nc + Na;           // 6144 = 48 * 128

    float4* P = (float4*)d_ws;

    prep<<<(Ntot + 255) / 256, 256, 0, stream>>>(cpos, crad, apos, ahalf,
                                                 P, (float2*)d_out, Nc, Ntot);

    // 96 body groups x 12 blocks x 4 waves = 48 chunk-pair slots per body group
    const int gx = (Ntot + 63) / 64;      // 96
    const int gy = 12;                    // 12*4 waves = 48 chunk-pairs
    dim3 grid(gx, gy, 1);
    collide<<<grid, 256, 0, stream>>>(P, (float*)d_out, Nc);
}

// Round 9
// 76.968 us; speedup vs baseline: 1.1044x; 1.1044x over previous
//
#include <hip/hip_runtime.h>
#include <math.h>

#define EPS 1e-9f

// P[i]: circle i<Nc -> (x, y, radius, 0); box -> (x, y, half.x, half.y).
// Also seeds out with base positions (collide atomically adds corrections).
__global__ void prep(const float2* __restrict__ cpos,
                     const float*  __restrict__ crad,
                     const float2* __restrict__ apos,
                     const float2* __restrict__ ahalf,
                     float4* __restrict__ P,
                     float2* __restrict__ out,
                     int Nc, int Ntot) {
    int i = blockIdx.x * blockDim.x + threadIdx.x;
    if (i >= Ntot) return;
    if (i < Nc) {
        const float2 p = cpos[i];
        P[i]   = make_float4(p.x, p.y, crad[i], 0.0f);
        out[i] = p;
    } else {
        const float2 a = apos[i - Nc];
        const float2 h = ahalf[i - Nc];
        P[i]   = make_float4(a.x, a.y, h.x, h.y);
        out[i] = a;
    }
}

__device__ __forceinline__ int tri_off(int I) { return I * (193 - I) / 2; }  // T=96 tiles

// force on circle (px,py,ri) from circle q
__device__ __forceinline__ void f_cc(float px, float py, float ri,
                                     const float4& q, float& fx, float& fy) {
    const float dx = px - q.x, dy = py - q.y;
    const float d2 = fmaf(dx, dx, dy * dy);
    const float r  = __builtin_amdgcn_rsqf(d2);
    const float t  = fmaf(-d2, r, ri + q.z);
    float s = fmaxf(0.5f * t * r, 0.0f);
    s = (d2 > EPS) ? s : 0.0f;
    fx = s * dx; fy = s * dy;
}
// force on circle (px,py,ri) from box q
__device__ __forceinline__ void f_cb(float px, float py, float ri,
                                     const float4& q, float& fx, float& fy) {
    const float rx = px - q.x, ry = py - q.y;
    const float cx = fminf(fmaxf(rx, -q.z), q.z);
    const float cy = fminf(fmaxf(ry, -q.w), q.w);
    const float dx = rx - cx, dy = ry - cy;
    const float d2 = fmaf(dx, dx, dy * dy);
    const float r  = __builtin_amdgcn_rsqf(d2);
    const float t  = fmaf(-d2, r, ri);
    float s = fmaxf(0.5f * t * r, 0.0f);
    s = (d2 > EPS) ? s : 0.0f;
    fx = s * dx; fy = s * dy;
}
// force on box (bx,by,hx,hy) from box q
__device__ __forceinline__ void f_bb(float bx, float by, float hx, float hy,
                                     const float4& q, float& fx, float& fy) {
    const float dax = bx - q.x, day = by - q.y;
    const float ovx = (hx + q.z) - fabsf(dax);
    const float ovy = (hy + q.w) - fabsf(day);
    const bool hit = fminf(ovx, ovy) > 0.0f;
    const bool ux  = ovx <= ovy;
    fx = (hit && ux)  ? copysignf(0.5f * ovx, dax) : 0.0f;
    fy = (hit && !ux) ? copysignf(0.5f * ovy, day) : 0.0f;
}

// Symmetric tile-pair kernel: wave t handles unordered tile pair (I<=J) of the
// 96 body tiles (64 bodies each; tiles 0..63 circles, 64..95 boxes). Lane=I-body
// in registers; J-tile staged DOUBLED in per-wave LDS (rotated index without &).
// Off-diagonal: each pair computed once; +f to lane body (register), -f to the
// J-body via 8-slot register batches flushed into per-wave LDS FJ (one cross-lane
// LDS dependency per 8 pairs). Diagonal: pure gather k=1..63. One atomic flush
// per wave. No __syncthreads anywhere. Forces are antisymmetric (exact for
// cc/cb; a.e. for bb sign ties).
__global__ __launch_bounds__(256)
void collide(const float4* __restrict__ P,
             float* __restrict__ out,
             int Nc) {
    const int lane = threadIdx.x & 63;
    const int w    = threadIdx.x >> 6;
    const int t    = blockIdx.x * 4 + w;          // tile-pair id, 0..4655 (uniform)

    // triangular decode t -> (I, J), I <= J
    int I = (int)((193.0 - sqrt(37249.0 - 8.0 * (double)t)) * 0.5);
    while (tri_off(I + 1) <= t) ++I;
    while (tri_off(I) > t) --I;
    const int J = I + (t - tri_off(I));

    const int tileC = Nc >> 6;                    // 64 circle tiles
    const bool bodyC = I < tileC;                 // uniform
    const bool partC = J < tileC;                 // uniform

    __shared__ float4 Jd[4][128];
    __shared__ float2 FJ[4][64];

    // stage J tile (doubled) + zero FJ; per-wave data, wave-synchronous -> no barrier
    {
        const float4 q = P[(J << 6) + lane];
        Jd[w][lane]      = q;
        Jd[w][lane + 64] = q;
        FJ[w][lane] = make_float2(0.0f, 0.0f);
    }
    const float4 me = P[(I << 6) + lane];

    float ax = 0.0f, ay = 0.0f;

    if (I != J) {
        if (bodyC && partC) {               // CC
            const float px = me.x, py = me.y, ri = me.z;
            for (int b = 0; b < 8; ++b) {
                const int base = lane + (b << 3);
                float sx[8], sy[8];
                #pragma unroll
                for (int s = 0; s < 8; ++s) {
                    const float4 q = Jd[w][base + s];
                    float fx, fy; f_cc(px, py, ri, q, fx, fy);
                    ax += fx; ay += fy;
                    sx[s] = -fx; sy[s] = -fy;
                }
                #pragma unroll
                for (int s = 0; s < 8; ++s) {
                    const int jj = (base + s) & 63;
                    float2 g = FJ[w][jj];
                    g.x += sx[s]; g.y += sy[s];
                    FJ[w][jj] = g;
                }
            }
        } else if (bodyC) {                 // CB: I circle tile, J box tile
            const float px = me.x, py = me.y, ri = me.z;
            for (int b = 0; b < 8; ++b) {
                const int base = lane + (b << 3);
                float sx[8], sy[8];
                #pragma unroll
                for (int s = 0; s < 8; ++s) {
                    const float4 q = Jd[w][base + s];
                    float fx, fy; f_cb(px, py, ri, q, fx, fy);
                    ax += fx; ay += fy;
                    sx[s] = -fx; sy[s] = -fy;
                }
                #pragma unroll
                for (int s = 0; s < 8; ++s) {
                    const int jj = (base + s) & 63;
                    float2 g = FJ[w][jj];
                    g.x += sx[s]; g.y += sy[s];
                    FJ[w][jj] = g;
                }
            }
        } else {                            // BB
            const float bx = me.x, by = me.y, hx = me.z, hy = me.w;
            for (int b = 0; b < 8; ++b) {
                const int base = lane + (b << 3);
                float sx[8], sy[8];
                #pragma unroll
                for (int s = 0; s < 8; ++s) {
                    const float4 q = Jd[w][base + s];
                    float fx, fy; f_bb(bx, by, hx, hy, q, fx, fy);
                    ax += fx; ay += fy;
                    sx[s] = -fx; sy[s] = -fy;
                }
                #pragma unroll
                for (int s = 0; s < 8; ++s) {
                    const int jj = (base + s) & 63;
                    float2 g = FJ[w][jj];
                    g.x += sx[s]; g.y += sy[s];
                    FJ[w][jj] = g;
                }
            }
        }
    } else {
        // diagonal tile: gather only, k=1..63 (self-pair skipped structurally)
        if (bodyC) {                        // CC diag
            const float px = me.x, py = me.y, ri = me.z;
            #pragma unroll 7
            for (int k = 1; k < 64; ++k) {
                const float4 q = Jd[w][lane + k];
                float fx, fy; f_cc(px, py, ri, q, fx, fy);
                ax += fx; ay += fy;
            }
        } else {                            // BB diag
            const float bx = me.x, by = me.y, hx = me.z, hy = me.w;
            #pragma unroll 7
            for (int k = 1; k < 64; ++k) {
                const float4 q = Jd[w][lane + k];
                float fx, fy; f_bb(bx, by, hx, hy, q, fx, fy);
                ax += fx; ay += fy;
            }
        }
    }

    // flush
    if (I != J) {
        const float2 g = FJ[w][lane];
        atomicAdd(&out[(((J << 6) + lane) << 1)],     g.x);
        atomicAdd(&out[(((J << 6) + lane) << 1) + 1], g.y);
    }
    atomicAdd(&out[(((I << 6) + lane) << 1)],     ax);
    atomicAdd(&out[(((I << 6) + lane) << 1) + 1], ay);
}

extern "C" void kernel_launch(void* const* d_in, const int* in_sizes, int n_in,
                              void* d_out, int out_size, void* d_ws, size_t ws_size,
                              hipStream_t stream) {
    (void)n_in; (void)out_size; (void)ws_size;

    const float2* cpos  = (const float2*)d_in[0];
    const float*  crad  = (const float*) d_in[1];
    const float2* apos  = (const float2*)d_in[2];
    const float2* ahalf = (const float2*)d_in[3];

    const int Nc   = in_sizes[1];       // 4096
    const int Na   = in_sizes[2] / 2;   // 2048
    const int Ntot = Nc + Na;           // 6144 = 96 tiles of 64

    float4* P = (float4*)d_ws;

    prep<<<(Ntot + 255) / 256, 256, 0, stream>>>(cpos, crad, apos, ahalf,
                                                 P, (float2*)d_out, Nc, Ntot);

    // 96 tiles -> 96*97/2 = 4656 unordered tile pairs, 4 waves/block
    const int tile_pairs = (96 * 97) / 2;       // 4656
    const int blocks = tile_pairs / 4;          // 1164
    collide<<<blocks, 256, 0, stream>>>(P, (float*)d_out, Nc);
}